// Round 1
// baseline (374.256 us; speedup 1.0000x reference)
//
#include <hip/hip_runtime.h>
#include <hip/hip_bf16.h>
#include <stdint.h>

// ---------------------------------------------------------------------------
// HeadAttention: Q=xq*W^T+b, K=xk*W^T+b, V=xv*W^T+b (same W,b),
// O = softmax(causal(Q K^T / 32)) V.    B=4, S=2048, E=1024, fp32 in/out.
// Strategy: bf16 MFMA (16x16x32) for all GEMMs, fp32 accumulate.
// ---------------------------------------------------------------------------

typedef __attribute__((ext_vector_type(8))) short bf16x8;
typedef __attribute__((ext_vector_type(4))) float floatx4;

#define DEVI static __device__ __forceinline__

static constexpr int S_ = 2048;
static constexpr int E_ = 1024;
static constexpr int BATCH = 4;

DEVI unsigned short f2b(float f) {
  union { float f; unsigned u; } v; v.f = f;
  return (unsigned short)((v.u + 0x7FFFu + ((v.u >> 16) & 1u)) >> 16); // RNE
}

DEVI void async_load16(const void* g, void* l) {
  __builtin_amdgcn_global_load_lds(
      (__attribute__((address_space(1))) void*)(void*)(g),
      (__attribute__((address_space(3))) void*)(l),
      16, 0, 0);
}

// 16 MFMAs on the staged 128x32 tiles; wave sub-tile (m0,n0), frag row lrow,
// frag k-offset lk. A/B frag layout: elem j of lane = Mat[lane&15][(lane>>4)*8+j].
DEVI void mfma_tile(const unsigned short* lsA, const unsigned short* lsB,
                    int m0, int n0, int lrow, int lk, floatx4 (&acc)[4][4]) {
  bf16x8 af[4], bfr[4];
#pragma unroll
  for (int i = 0; i < 4; ++i)
    af[i] = *(const bf16x8*)(lsA + (m0 + i * 16 + lrow) * 32 + lk);
#pragma unroll
  for (int i = 0; i < 4; ++i)
    bfr[i] = *(const bf16x8*)(lsB + (n0 + i * 16 + lrow) * 32 + lk);
#pragma unroll
  for (int mi = 0; mi < 4; ++mi)
#pragma unroll
    for (int ni = 0; ni < 4; ++ni)
      acc[mi][ni] = __builtin_amdgcn_mfma_f32_16x16x32_bf16(
          af[mi], bfr[ni], acc[mi][ni], 0, 0, 0);
}

// fp32 -> bf16 convert (for Wq), vectorized x4
__global__ void cvt_kernel(const float* __restrict__ src,
                           unsigned short* __restrict__ dst, int n4) {
  int i = blockIdx.x * blockDim.x + threadIdx.x;
  if (i < n4) {
    float4 v = ((const float4*)src)[i];
    ushort4 o;
    o.x = f2b(v.x); o.y = f2b(v.y); o.z = f2b(v.z); o.w = f2b(v.w);
    ((ushort4*)dst)[i] = o;
  }
}

// ---------------------------------------------------------------------------
// QKV linear: C[m,n] = sum_k A_f32[m,k] * W_bf16[n,k] + bias[n], M=8192,N=K=1024.
// A staged fp32->bf16 through registers; W via global_load_lds width 16.
// TRANS_STORE: store V transposed per batch: Vt[b][n][s], b=m>>11, s=m&2047.
// ---------------------------------------------------------------------------
template <bool TRANS_STORE>
__global__ __launch_bounds__(256, 2) void gemm_qkv(
    const float* __restrict__ A, const unsigned short* __restrict__ Bt,
    const float* __restrict__ bias, unsigned short* __restrict__ C) {
  __shared__ __align__(16) unsigned short lsA[128 * 32];
  __shared__ __align__(16) unsigned short lsB[128 * 32];
  const int tid = threadIdx.x;
  const int bm = blockIdx.y, bn = blockIdx.x;
  const int lane = tid & 63, wave = tid >> 6;
  const int m0 = (wave >> 1) * 64, n0 = (wave & 1) * 64;
  const int lrow = lane & 15, lk = (lane >> 4) * 8;

  floatx4 acc[4][4] = {};

  for (int kt = 0; kt < 1024 / 32; ++kt) {
    if (kt) __syncthreads();  // prior tile's ds_reads done before overwrite
    // stage W tile (async, 2 x 16B per thread)
#pragma unroll
    for (int j = 0; j < 2; ++j) {
      int t = tid + j * 256, row = t >> 2, kk = (t & 3) << 3;
      async_load16(Bt + (size_t)(bn * 128 + row) * 1024 + kt * 32 + kk,
                   lsB + t * 8);
    }
    // stage A tile: fp32 load -> bf16 -> ds_write (4 x float4 per thread)
#pragma unroll
    for (int j = 0; j < 4; ++j) {
      int t = tid + j * 256, row = t >> 3, kk = (t & 7) << 2;
      float4 v = *(const float4*)(A + (size_t)(bm * 128 + row) * 1024 +
                                  kt * 32 + kk);
      ushort4 o;
      o.x = f2b(v.x); o.y = f2b(v.y); o.z = f2b(v.z); o.w = f2b(v.w);
      *(ushort4*)(lsA + row * 32 + kk) = o;
    }
    __syncthreads();  // drains vmcnt (async loads) + lgkmcnt (ds_writes)
    mfma_tile(lsA, lsB, m0, n0, lrow, lk, acc);
  }

  const int rb = (lane >> 4) * 4;  // C/D: col=lane&15, row=(lane>>4)*4+reg
#pragma unroll
  for (int mi = 0; mi < 4; ++mi)
#pragma unroll
    for (int ni = 0; ni < 4; ++ni) {
      int gcol = bn * 128 + n0 + ni * 16 + lrow;
      float bv = bias[gcol];
#pragma unroll
      for (int r = 0; r < 4; ++r) {
        int grow = bm * 128 + m0 + mi * 16 + rb + r;
        unsigned short val = f2b(acc[mi][ni][r] + bv);
        if (TRANS_STORE) {
          int b = grow >> 11, s = grow & 2047;
          C[((size_t)b * 1024 + gcol) * 2048 + s] = val;
        } else {
          C[(size_t)grow * 1024 + gcol] = val;
        }
      }
    }
}

// ---------------------------------------------------------------------------
// bf16 x bf16 -> fp32 GEMM, B^T layout, batched via blockIdx.z.
// MODE 2 = scores (skip upper-triangular blocks, scale 1/32).
// MODE 3 = PV (K-loop truncated at (bm+1)*128; zeros in P beyond causal).
// ---------------------------------------------------------------------------
template <int MODE>
__global__ __launch_bounds__(256, 2) void gemm_bt(
    const unsigned short* __restrict__ Abase,
    const unsigned short* __restrict__ Btbase, float* __restrict__ Cbase,
    int lda, int ldb, int ldc, long strideA, long strideB, long strideC,
    float scale) {
  __shared__ __align__(16) unsigned short lsA[128 * 32];
  __shared__ __align__(16) unsigned short lsB[128 * 32];
  const int bm = blockIdx.y, bn = blockIdx.x, bz = blockIdx.z;
  if (MODE == 2 && bn > bm) return;  // fully-masked causal block: never read
  const unsigned short* A = Abase + (size_t)bz * strideA + (size_t)bm * 128 * lda;
  const unsigned short* Bt = Btbase + (size_t)bz * strideB + (size_t)bn * 128 * ldb;
  float* C = Cbase + (size_t)bz * strideC;
  const int tid = threadIdx.x;
  const int lane = tid & 63, wave = tid >> 6;
  const int m0 = (wave >> 1) * 64, n0 = (wave & 1) * 64;
  const int lrow = lane & 15, lk = (lane >> 4) * 8;

  floatx4 acc[4][4] = {};
  const int nK = (MODE == 3) ? (bm + 1) * 4 : 32;

  for (int kt = 0; kt < nK; ++kt) {
    if (kt) __syncthreads();
#pragma unroll
    for (int j = 0; j < 2; ++j) {
      int t = tid + j * 256, row = t >> 2, kk = (t & 3) << 3;
      async_load16(A + (size_t)row * lda + kt * 32 + kk, lsA + t * 8);
    }
#pragma unroll
    for (int j = 0; j < 2; ++j) {
      int t = tid + j * 256, row = t >> 2, kk = (t & 3) << 3;
      async_load16(Bt + (size_t)row * ldb + kt * 32 + kk, lsB + t * 8);
    }
    __syncthreads();
    mfma_tile(lsA, lsB, m0, n0, lrow, lk, acc);
  }

  const int rb = (lane >> 4) * 4;
#pragma unroll
  for (int mi = 0; mi < 4; ++mi)
#pragma unroll
    for (int ni = 0; ni < 4; ++ni) {
      int gcol = bn * 128 + n0 + ni * 16 + lrow;
#pragma unroll
      for (int r = 0; r < 4; ++r) {
        int grow = bm * 128 + m0 + mi * 16 + rb + r;
        C[(size_t)grow * ldc + gcol] = acc[mi][ni][r] * scale;
      }
    }
}

// ---------------------------------------------------------------------------
// Row softmax over scores (fp32), causal: only k<=q valid. Writes P as bf16
// IN PLACE at the row's start (row stride stays 8192 bytes = 4096 bf16),
// zero-padded up to round_up(q+1,128) so the PV GEMM reads defined zeros.
// ---------------------------------------------------------------------------
__global__ __launch_bounds__(256) void softmax_rows(float* __restrict__ Sc) {
  const int r = blockIdx.x;  // b*2048 + q
  const int q = r & (S_ - 1);
  float* srow = Sc + (size_t)r * S_;
  __shared__ float buf[S_];
  __shared__ float red[8];
  const int tid = threadIdx.x, lane = tid & 63, wv = tid >> 6;
  const int n = q + 1;

  float mx = -1e30f;
  for (int k = tid; k < n; k += 256) {
    float v = srow[k];
    buf[k] = v;
    mx = fmaxf(mx, v);
  }
#pragma unroll
  for (int off = 32; off; off >>= 1) mx = fmaxf(mx, __shfl_xor(mx, off));
  if (lane == 0) red[wv] = mx;
  __syncthreads();
  mx = fmaxf(fmaxf(red[0], red[1]), fmaxf(red[2], red[3]));

  float sum = 0.f;
  for (int k = tid; k < n; k += 256) {
    float e = __expf(buf[k] - mx);
    buf[k] = e;
    sum += e;
  }
#pragma unroll
  for (int off = 32; off; off >>= 1) sum += __shfl_xor(sum, off);
  if (lane == 0) red[4 + wv] = sum;
  __syncthreads();  // also orders: all fp32 reads of srow complete before write
  sum = red[4] + red[5] + red[6] + red[7];
  const float inv = 1.0f / sum;

  unsigned short* prow = (unsigned short*)srow;  // bf16 P, same row base
  const int kmax = (q & ~127) + 128;             // round_up(q+1, 128)
  for (int k = tid; k < kmax; k += 256)
    prow[k] = (k < n) ? f2b(buf[k] * inv) : (unsigned short)0;
}

// ---------------------------------------------------------------------------
extern "C" void kernel_launch(void* const* d_in, const int* in_sizes, int n_in,
                              void* d_out, int out_size, void* d_ws,
                              size_t ws_size, hipStream_t stream) {
  (void)in_sizes; (void)n_in; (void)out_size; (void)ws_size;
  const float* xq = (const float*)d_in[0];
  const float* xk = (const float*)d_in[1];
  const float* xv = (const float*)d_in[2];
  const float* Wq = (const float*)d_in[3];
  const float* bq = (const float*)d_in[4];
  // d_in[5] att_mask: exact triu(k=1) causal mask, computed analytically.
  float* out = (float*)d_out;

  // workspace layout (bytes): Wb 2M | Q 16M | K 16M | Vt 16M | Sc 64M = 114MB
  unsigned short* Wb = (unsigned short*)d_ws;
  unsigned short* Qb = Wb + (size_t)1024 * 1024;
  unsigned short* Kb = Qb + (size_t)8192 * 1024;
  unsigned short* Vt = Kb + (size_t)8192 * 1024;
  float* Sc = (float*)(Vt + (size_t)8192 * 1024);

  cvt_kernel<<<(1024 * 1024 / 4) / 256, 256, 0, stream>>>(Wq, Wb,
                                                          1024 * 1024 / 4);
  dim3 g0(8, 64);  // N/128, M/128
  gemm_qkv<false><<<g0, 256, 0, stream>>>(xq, Wb, bq, Qb);
  gemm_qkv<false><<<g0, 256, 0, stream>>>(xk, Wb, bq, Kb);
  gemm_qkv<true><<<g0, 256, 0, stream>>>(xv, Wb, bq, Vt);

  dim3 g1(16, 16, BATCH);  // S/128 x S/128 x B
  gemm_bt<2><<<g1, 256, 0, stream>>>(Qb, Kb, Sc, E_, E_, S_,
                                     (long)S_ * E_, (long)S_ * E_,
                                     (long)S_ * S_, 0.03125f);

  softmax_rows<<<BATCH * S_, 256, 0, stream>>>(Sc);

  dim3 g2(8, 16, BATCH);  // E/128 x S/128 x B
  gemm_bt<3><<<g2, 256, 0, stream>>>((const unsigned short*)Sc, Vt, out,
                                     2 * S_, S_, E_, (long)S_ * 2 * S_,
                                     (long)E_ * S_, (long)S_ * E_, 1.0f);
}

// Round 2
// 340.966 us; speedup vs baseline: 1.0976x; 1.0976x over previous
//
#include <hip/hip_runtime.h>
#include <hip/hip_bf16.h>
#include <stdint.h>

// ---------------------------------------------------------------------------
// HeadAttention: Q=xq*W^T+b, K=xk*W^T+b, V=xv*W^T+b (same W,b),
// O = softmax(causal(Q K^T / 32)) V.    B=4, S=2048, E=1024, fp32 in/out.
// bf16 MFMA 16x16x32 for all GEMMs, fp32 accumulate.
// R2: XCD-aware swizzles (bid%8 -> XCD assumption); fused single QKV dispatch.
// ---------------------------------------------------------------------------

typedef __attribute__((ext_vector_type(8))) short bf16x8;
typedef __attribute__((ext_vector_type(4))) float floatx4;

#define DEVI static __device__ __forceinline__

static constexpr int S_ = 2048;
static constexpr int E_ = 1024;
static constexpr int BATCH = 4;

DEVI unsigned short f2b(float f) {
  union { float f; unsigned u; } v; v.f = f;
  return (unsigned short)((v.u + 0x7FFFu + ((v.u >> 16) & 1u)) >> 16); // RNE
}

DEVI void async_load16(const void* g, void* l) {
  __builtin_amdgcn_global_load_lds(
      (__attribute__((address_space(1))) void*)(void*)(g),
      (__attribute__((address_space(3))) void*)(l),
      16, 0, 0);
}

// 16 MFMAs on staged 128x32 tiles. A/B frag: elem j = Mat[lane&15][(lane>>4)*8+j].
DEVI void mfma_tile(const unsigned short* lsA, const unsigned short* lsB,
                    int m0, int n0, int lrow, int lk, floatx4 (&acc)[4][4]) {
  bf16x8 af[4], bfr[4];
#pragma unroll
  for (int i = 0; i < 4; ++i)
    af[i] = *(const bf16x8*)(lsA + (m0 + i * 16 + lrow) * 32 + lk);
#pragma unroll
  for (int i = 0; i < 4; ++i)
    bfr[i] = *(const bf16x8*)(lsB + (n0 + i * 16 + lrow) * 32 + lk);
#pragma unroll
  for (int mi = 0; mi < 4; ++mi)
#pragma unroll
    for (int ni = 0; ni < 4; ++ni)
      acc[mi][ni] = __builtin_amdgcn_mfma_f32_16x16x32_bf16(
          af[mi], bfr[ni], acc[mi][ni], 0, 0, 0);
}

// stage a 128x32 bf16 tile (async, 2 x 16B per thread), rows stride `ld`
DEVI void stage_bf16(const unsigned short* src, unsigned short* ls, int ld,
                     int tid) {
#pragma unroll
  for (int j = 0; j < 2; ++j) {
    int t = tid + j * 256, row = t >> 2, kk = (t & 3) << 3;
    async_load16(src + (size_t)row * ld + kk, ls + t * 8);
  }
}

// fp32 -> bf16 convert (for Wq), vectorized x4
__global__ void cvt_kernel(const float* __restrict__ src,
                           unsigned short* __restrict__ dst, int n4) {
  int i = blockIdx.x * blockDim.x + threadIdx.x;
  if (i < n4) {
    float4 v = ((const float4*)src)[i];
    ushort4 o;
    o.x = f2b(v.x); o.y = f2b(v.y); o.z = f2b(v.z); o.w = f2b(v.w);
    ((ushort4*)dst)[i] = o;
  }
}

// ---------------------------------------------------------------------------
// Fused QKV linear: one dispatch, 1536 blocks. Swizzle: xcd=l&7; the 8 bn
// blocks sharing an (input,bm) fp32 A-tile sit at stride-8 => same XCD L2.
//   l&7 = xcd, i=l>>3: bn=i&7, bmg=xcd*24+(i>>3); input=bmg/64, bm=bmg%64.
// V (input==2) stored transposed per batch: Vt[b][e][s].
// ---------------------------------------------------------------------------
__global__ __launch_bounds__(256, 2) void gemm_qkv(
    const float* __restrict__ xq, const float* __restrict__ xk,
    const float* __restrict__ xv, const unsigned short* __restrict__ Wb,
    const float* __restrict__ bias, unsigned short* __restrict__ Qb,
    unsigned short* __restrict__ Kb, unsigned short* __restrict__ Vt) {
  __shared__ __align__(16) unsigned short lsA[128 * 32];
  __shared__ __align__(16) unsigned short lsB[128 * 32];
  const int l = blockIdx.x;
  const int xcd = l & 7, i = l >> 3;
  const int bn = i & 7;
  const int bmg = xcd * 24 + (i >> 3);
  const int input = bmg / 64, bm = bmg % 64;
  const float* A = (input == 0) ? xq : (input == 1) ? xk : xv;
  A += (size_t)bm * 128 * 1024;

  const int tid = threadIdx.x;
  const int lane = tid & 63, wave = tid >> 6;
  const int m0 = (wave >> 1) * 64, n0 = (wave & 1) * 64;
  const int lrow = lane & 15, lk = (lane >> 4) * 8;

  floatx4 acc[4][4] = {};

  for (int kt = 0; kt < 1024 / 32; ++kt) {
    if (kt) __syncthreads();  // prior tile's ds_reads done before overwrite
    stage_bf16(Wb + (size_t)bn * 128 * 1024 + kt * 32, lsB, 1024, tid);
    // stage A tile: fp32 load -> bf16 -> ds_write (4 x float4 per thread)
#pragma unroll
    for (int j = 0; j < 4; ++j) {
      int t = tid + j * 256, row = t >> 3, kk = (t & 7) << 2;
      float4 v = *(const float4*)(A + (size_t)row * 1024 + kt * 32 + kk);
      ushort4 o;
      o.x = f2b(v.x); o.y = f2b(v.y); o.z = f2b(v.z); o.w = f2b(v.w);
      *(ushort4*)(lsA + row * 32 + kk) = o;
    }
    __syncthreads();  // drains vmcnt (async) + lgkmcnt (ds_writes)
    mfma_tile(lsA, lsB, m0, n0, lrow, lk, acc);
  }

  unsigned short* C = (input == 0) ? Qb : (input == 1) ? Kb : Vt;
  const int rb = (lane >> 4) * 4;  // C/D: col=lane&15, row=(lane>>4)*4+reg
#pragma unroll
  for (int mi = 0; mi < 4; ++mi)
#pragma unroll
    for (int ni = 0; ni < 4; ++ni) {
      int gcol = bn * 128 + n0 + ni * 16 + lrow;
      float bv = bias[gcol];
#pragma unroll
      for (int r = 0; r < 4; ++r) {
        int grow = bm * 128 + m0 + mi * 16 + rb + r;
        unsigned short val = f2b(acc[mi][ni][r] + bv);
        if (input == 2) {
          int b = grow >> 11, s = grow & 2047;
          C[((size_t)b * 1024 + gcol) * 2048 + s] = val;
        } else {
          C[(size_t)grow * 1024 + gcol] = val;
        }
      }
    }
}

// ---------------------------------------------------------------------------
// Scores: Sc[z][q,k] = (Q K^T)/32, lower-tri 128-blocks only. 768 blocks with
// padded-group swizzle: xcd=l&7, k=l>>3, m=k&7, gl=k>>3; gg=xcd*12+gl;
// z=gg/24, r=gg%24; bm=r<8?r:8+((r-8)>>1); bn=(r<8?0:((r-8)&1))*8+m.
// 2 XCDs per batch; groups of 8 bn share a Q tile on one XCD.
// ---------------------------------------------------------------------------
__global__ __launch_bounds__(256, 2) void gemm_scores(
    const unsigned short* __restrict__ Qb,
    const unsigned short* __restrict__ Kb, float* __restrict__ Sc) {
  const int l = blockIdx.x;
  const int xcd = l & 7, k = l >> 3;
  const int m = k & 7, gl = k >> 3;
  const int gg = xcd * 12 + gl;
  const int z = gg / 24, r = gg % 24;
  const int bm = (r < 8) ? r : 8 + ((r - 8) >> 1);
  const int bn = ((r < 8) ? 0 : ((r - 8) & 1)) * 8 + m;
  if (bn > bm) return;

  __shared__ __align__(16) unsigned short lsA[128 * 32];
  __shared__ __align__(16) unsigned short lsB[128 * 32];
  const unsigned short* A = Qb + ((size_t)z * S_ + bm * 128) * E_;
  const unsigned short* Bt = Kb + ((size_t)z * S_ + bn * 128) * E_;
  float* C = Sc + (size_t)z * S_ * S_;
  const int tid = threadIdx.x;
  const int lane = tid & 63, wave = tid >> 6;
  const int m0 = (wave >> 1) * 64, n0 = (wave & 1) * 64;
  const int lrow = lane & 15, lk = (lane >> 4) * 8;

  floatx4 acc[4][4] = {};
  for (int kt = 0; kt < 32; ++kt) {
    if (kt) __syncthreads();
    stage_bf16(A + kt * 32, lsA, E_, tid);
    stage_bf16(Bt + kt * 32, lsB, E_, tid);
    __syncthreads();
    mfma_tile(lsA, lsB, m0, n0, lrow, lk, acc);
  }

  const int rb = (lane >> 4) * 4;
#pragma unroll
  for (int mi = 0; mi < 4; ++mi)
#pragma unroll
    for (int ni = 0; ni < 4; ++ni) {
      int gcol = bn * 128 + n0 + ni * 16 + lrow;
#pragma unroll
      for (int r = 0; r < 4; ++r) {
        int grow = bm * 128 + m0 + mi * 16 + rb + r;
        C[(size_t)grow * S_ + gcol] = acc[mi][ni][r] * 0.03125f;
      }
    }
}

// ---------------------------------------------------------------------------
// PV: out[z][q,e] = P V, K truncated at (bm+1)*128 (causal zeros beyond).
// 512 blocks: xcd=l&7, i=l>>3, bn=i&7, bmg=xcd*8+(i>>3); z=bmg>>4, bm=bmg&15.
// Groups of 8 bn share a P tile on one XCD; 2 XCDs per batch (Vt reuse).
// ---------------------------------------------------------------------------
__global__ __launch_bounds__(256, 2) void gemm_pv(
    const unsigned short* __restrict__ Pb,
    const unsigned short* __restrict__ Vt, float* __restrict__ Out) {
  __shared__ __align__(16) unsigned short lsA[128 * 32];
  __shared__ __align__(16) unsigned short lsB[128 * 32];
  const int l = blockIdx.x;
  const int xcd = l & 7, i = l >> 3;
  const int bn = i & 7;
  const int bmg = xcd * 8 + (i >> 3);
  const int z = bmg >> 4, bm = bmg & 15;

  const unsigned short* A = Pb + ((size_t)z * S_ + bm * 128) * (2 * S_);
  const unsigned short* Bt = Vt + ((size_t)z * E_ + bn * 128) * S_;
  float* C = Out + (size_t)z * S_ * E_;
  const int tid = threadIdx.x;
  const int lane = tid & 63, wave = tid >> 6;
  const int m0 = (wave >> 1) * 64, n0 = (wave & 1) * 64;
  const int lrow = lane & 15, lk = (lane >> 4) * 8;

  floatx4 acc[4][4] = {};
  const int nK = (bm + 1) * 4;
  for (int kt = 0; kt < nK; ++kt) {
    if (kt) __syncthreads();
    stage_bf16(A + kt * 32, lsA, 2 * S_, tid);
    stage_bf16(Bt + kt * 32, lsB, S_, tid);
    __syncthreads();
    mfma_tile(lsA, lsB, m0, n0, lrow, lk, acc);
  }

  const int rb = (lane >> 4) * 4;
#pragma unroll
  for (int mi = 0; mi < 4; ++mi)
#pragma unroll
    for (int ni = 0; ni < 4; ++ni) {
      int gcol = bn * 128 + n0 + ni * 16 + lrow;
#pragma unroll
      for (int r = 0; r < 4; ++r) {
        int grow = bm * 128 + m0 + mi * 16 + rb + r;
        C[(size_t)grow * E_ + gcol] = acc[mi][ni][r];
      }
    }
}

// ---------------------------------------------------------------------------
// Row softmax over scores (fp32), causal: only k<=q valid. Writes P as bf16
// IN PLACE at the row's start (row stride stays 4096 bf16), zero-padded to
// round_up(q+1,128) so the PV GEMM reads defined zeros.
// ---------------------------------------------------------------------------
__global__ __launch_bounds__(256) void softmax_rows(float* __restrict__ Sc) {
  const int r = blockIdx.x;  // b*2048 + q
  const int q = r & (S_ - 1);
  float* srow = Sc + (size_t)r * S_;
  __shared__ float buf[S_];
  __shared__ float red[8];
  const int tid = threadIdx.x, lane = tid & 63, wv = tid >> 6;
  const int n = q + 1;

  float mx = -1e30f;
  for (int k = tid; k < n; k += 256) {
    float v = srow[k];
    buf[k] = v;
    mx = fmaxf(mx, v);
  }
#pragma unroll
  for (int off = 32; off; off >>= 1) mx = fmaxf(mx, __shfl_xor(mx, off));
  if (lane == 0) red[wv] = mx;
  __syncthreads();
  mx = fmaxf(fmaxf(red[0], red[1]), fmaxf(red[2], red[3]));

  float sum = 0.f;
  for (int k = tid; k < n; k += 256) {
    float e = __expf(buf[k] - mx);
    buf[k] = e;
    sum += e;
  }
#pragma unroll
  for (int off = 32; off; off >>= 1) sum += __shfl_xor(sum, off);
  if (lane == 0) red[4 + wv] = sum;
  __syncthreads();  // also orders: all fp32 reads of srow done before write
  sum = red[4] + red[5] + red[6] + red[7];
  const float inv = 1.0f / sum;

  unsigned short* prow = (unsigned short*)srow;  // bf16 P, same row base
  const int kmax = (q & ~127) + 128;             // round_up(q+1, 128)
  for (int k = tid; k < kmax; k += 256)
    prow[k] = (k < n) ? f2b(buf[k] * inv) : (unsigned short)0;
}

// ---------------------------------------------------------------------------
extern "C" void kernel_launch(void* const* d_in, const int* in_sizes, int n_in,
                              void* d_out, int out_size, void* d_ws,
                              size_t ws_size, hipStream_t stream) {
  (void)in_sizes; (void)n_in; (void)out_size; (void)ws_size;
  const float* xq = (const float*)d_in[0];
  const float* xk = (const float*)d_in[1];
  const float* xv = (const float*)d_in[2];
  const float* Wq = (const float*)d_in[3];
  const float* bq = (const float*)d_in[4];
  // d_in[5] att_mask: exact triu(k=1) causal mask, handled analytically.
  float* out = (float*)d_out;

  // workspace (bytes): Wb 2M | Q 16M | K 16M | Vt 16M | Sc 64M = 114MB
  unsigned short* Wb = (unsigned short*)d_ws;
  unsigned short* Qb = Wb + (size_t)1024 * 1024;
  unsigned short* Kb = Qb + (size_t)8192 * 1024;
  unsigned short* Vt = Kb + (size_t)8192 * 1024;
  float* Sc = (float*)(Vt + (size_t)8192 * 1024);

  cvt_kernel<<<(1024 * 1024 / 4) / 256, 256, 0, stream>>>(Wq, Wb,
                                                          1024 * 1024 / 4);
  gemm_qkv<<<1536, 256, 0, stream>>>(xq, xk, xv, Wb, bq, Qb, Kb, Vt);
  gemm_scores<<<768, 256, 0, stream>>>(Qb, Kb, Sc);
  softmax_rows<<<BATCH * S_, 256, 0, stream>>>(Sc);
  gemm_pv<<<512, 256, 0, stream>>>((const unsigned short*)Sc, Vt, out);
}